// Round 1
// 843.962 us; speedup vs baseline: 1.1465x; 1.1465x over previous
//
#include <hip/hip_runtime.h>
#include <hip/hip_bf16.h>
#include <math.h>

// Problem constants: T=2048, B=4096, IN_S=1, H=20, OUT_S=1
#define TT 2048
#define BB 4096
#define HH 20

typedef float v2f __attribute__((ext_vector_type(2)));

#define L2E 1.4426950408889634f  // log2(e)

__device__ __forceinline__ float rcp_fast(float x)  { return __builtin_amdgcn_rcpf(x); }
__device__ __forceinline__ float exp2_fast(float x) { return __builtin_amdgcn_exp2f(x); }

// Backend selects v_pk_fma_f32 — no inline-asm pinning (R5 lesson).
__device__ __forceinline__ v2f pk_fma(v2f a, v2f b, v2f c) {
    return __builtin_elementwise_fma(a, b, c);
}

// One wave per block, TWO batches per wave (lanes [0..19],[20..39]).
// R9 changes vs the 967us kernel:
//  (a) y-offload: lanes 40/41 (previously idle) carry W_out as their gate-0
//      row (unscaled, u-term zeroed) and read group 0/1's h broadcast, so
//      their a0 accumulator IS y. Drops the redundant ay dot (50->40 pk_fma)
//      and the per-step y extraction on worker lanes.
//  (b) merged denominators: c' and h each use ONE rcp (5 rcp -> 2 total):
//      c' = [c*(1+eg)(1+ei) + (1-eg)(1+ef)] / [(1+ef)(1+ei)(1+eg)]
//      h  = copysign(1-ec, c) / [(1+eo)(1+ec)]
//      g-row prescale is now -2*L2E so (1-eg)/(1+eg) is sign-correct with no
//      abs/copysign. c-tanh keeps the |c| form (ec<=1) — overflow-safe.
//  (c) accumulator init via pk_mul of {gsc*wih,0} x {u,u} (no zero-movs).
// R4/R8 lesson retained: the per-step serial stall is hidden by the OTHER
// resident wave; 2048 blocks = exactly 2 waves/SIMD chip-wide.
__global__ __launch_bounds__(64, 2) void lstm_fused_kernel(
    const float* __restrict__ u,      // [T, B, 1]
    const float* __restrict__ W_ih,   // [4H, 1]
    const float* __restrict__ W_hh,   // [4H, H]
    const float* __restrict__ W_out,  // [1, H]
    float* __restrict__ y)            // [T, B, 1]
{
    // Single buffer. Compiler SEES the aliasing between write and reads ->
    // inserts the lgkmcnt wait itself (R6-verified correct; R7 showed
    // __restrict__ LDS pointers suppress it -> stale h).
    __shared__ __align__(16) float hbuf[4][HH];

    const int lane  = threadIdx.x;
    const int group = lane / HH;          // 0..3 (2,3 == y/idle)
    const int j     = lane - group * HH;  // 0..19
    const bool is_y = (lane >= 2 * HH) && (lane < 2 * HH + 2);  // lanes 40,41
    const int b_real = blockIdx.x * 2 + group;
    const bool active = (group < 2) && (b_real < BB);
    const int b = active ? b_real : 0;

    // h_{-1} = 0 (all groups incl. idle regions).
    for (int i = lane; i < 4 * HH; i += 64) ((float*)hbuf)[i] = 0.0f;
    asm volatile("" ::: "memory");

    // ---- Weights in registers, packed along k: wg[g][m] = (w[2m], w[2m+1]).
    // Pre-scaled into exp2 domain: i,f,o rows * -log2(e); g row * -2*log2(e).
    v2f wg[4][HH / 2];
    const float gsc[4] = {-L2E, -L2E, -2.0f * L2E, -L2E};
    #pragma unroll
    for (int g = 0; g < 4; ++g) {
        #pragma unroll
        for (int m = 0; m < HH / 2; ++m) {
            wg[g][m].x = gsc[g] * W_hh[(g * HH + j) * HH + 2 * m];
            wg[g][m].y = gsc[g] * W_hh[(g * HH + j) * HH + 2 * m + 1];
        }
    }
    v2f wih2[4];
    #pragma unroll
    for (int g = 0; g < 4; ++g) { wih2[g].x = gsc[g] * W_ih[g * HH + j]; wih2[g].y = 0.0f; }

    // y-offload wiring: broadcast-source group per lane, W_out row for y-lanes.
    int bg = group;
    if (lane >= 2 * HH) {
        bg = is_y ? (lane - 2 * HH) : 2;  // lane40->group0's h, lane41->group1's
        if (is_y) {
            #pragma unroll
            for (int m = 0; m < HH / 2; ++m) {
                wg[0][m].x = W_out[2 * m];      // UNSCALED: a0 = dot(W_out, h)
                wg[0][m].y = W_out[2 * m + 1];
            }
            wih2[0].x = 0.0f;  // y has no u-term
        }
    }
    const v2f* hs = (const v2f*)(&hbuf[bg][0]);  // no restrict: must alias

    float c = 0.0f;
    const float* __restrict__ up = u + b;
    float* yp = y + blockIdx.x * 2 + (lane - 2 * HH);  // valid only on y-lanes

    float u_cur[4];
    #pragma unroll
    for (int k = 0; k < 4; ++k) u_cur[k] = up[(size_t)k * BB];

    for (int t4 = 0; t4 < TT; t4 += 4) {
        const int tn = (t4 + 4 < TT) ? (t4 + 4) : t4;
        float u_nxt[4];
        #pragma unroll
        for (int k = 0; k < 4; ++k) u_nxt[k] = up[(size_t)(tn + k) * BB];

        float y4[4];  // on y-lanes: y4[tt] = y_{t4+tt-1} (h broadcast read is one step late)

        #pragma unroll
        for (int tt = 0; tt < 4; ++tt) {
            // ---- read h_{t-1} as 10 pairs (compiler merges to ds_read_b128) ----
            v2f h2[10];
            #pragma unroll
            for (int m = 0; m < 10; ++m) h2[m] = hs[m];

            const float uv = u_cur[tt];
            const v2f uv2 = {uv, uv};
            v2f a0 = wih2[0] * uv2;   // v_pk_mul_f32; .y term is 0
            v2f a1 = wih2[1] * uv2;
            v2f a2 = wih2[2] * uv2;
            v2f a3 = wih2[3] * uv2;

            // 40 v_pk_fma_f32; 4 accumulators round-robin -> dep spacing
            // 4 insts (8 cyc) > 4-cyc FMA latency.
            #pragma unroll
            for (int m = 0; m < 10; ++m) {
                v2f hp = h2[m];
                a0 = pk_fma(wg[0][m], hp, a0);
                a1 = pk_fma(wg[1][m], hp, a1);
                a2 = pk_fma(wg[2][m], hp, a2);
                a3 = pk_fma(wg[3][m], hp, a3);
            }
            const float g0 = a0.x + a0.y;  // exp2-domain pre-acts (y-lanes: y value)
            const float g1 = a1.x + a1.y;
            const float g2 = a2.x + a2.y;
            const float g3 = a3.x + a3.y;
            y4[tt] = g0;                   // only consumed on y-lanes

            // ---- activations: 5 exp2, 2 rcp (merged denominators) ----
            const float ei = exp2_fast(g0);   // e^{-x_i}
            const float ef = exp2_fast(g1);   // e^{-x_f}
            const float eg = exp2_fast(g2);   // e^{-2 x_g}  (sign-safe: |x_g|<~6)
            const float eo = exp2_fast(g3);   // e^{-x_o}
            const float pi_ = 1.0f + ei;
            const float pf  = 1.0f + ef;
            const float pg  = 1.0f + eg;
            const float po  = 1.0f + eo;
            const float mg  = 1.0f - eg;      // sign of tanh(x_g) falls out naturally

            // c' = f*c + i*tanh(g), one rcp:
            const float m1  = pg * pi_;
            const float num = fmaf(c, m1, mg * pf);
            c = num * rcp_fast(pf * m1);

            // h = sigmoid(o)*tanh(c), one rcp; |c| form keeps ec<=1 (no overflow):
            const float ec  = exp2_fast(-2.0f * L2E * fabsf(c));
            const float pc  = 1.0f + ec;
            const float mcs = copysignf(1.0f - ec, c);
            const float h   = mcs * rcp_fast(po * pc);

            // ---- broadcast h_t (compiler inserts the lgkmcnt wait: it sees
            // the write/read aliasing) ----
            hbuf[group][j] = h;
            asm volatile("" ::: "memory");
        }

        if (is_y) {
            #pragma unroll
            for (int k = 0; k < 4; ++k) {
                const int idx = t4 - 1 + k;
                if (idx >= 0) yp[(size_t)idx * BB] = y4[k];
            }
        }

        #pragma unroll
        for (int k = 0; k < 4; ++k) u_cur[k] = u_nxt[k];
    }

    // Epilogue: y_{T-1} from the final h broadcast (y-lanes only).
    {
        v2f ay = {0.0f, 0.0f};
        #pragma unroll
        for (int m = 0; m < 10; ++m) ay = pk_fma(wg[0][m], hs[m], ay);
        if (is_y) yp[(size_t)(TT - 1) * BB] = ay.x + ay.y;
    }
}

extern "C" void kernel_launch(void* const* d_in, const int* in_sizes, int n_in,
                              void* d_out, int out_size, void* d_ws, size_t ws_size,
                              hipStream_t stream) {
    const float* u     = (const float*)d_in[0];   // [2048, 4096, 1]
    const float* W_ih  = (const float*)d_in[1];   // [80, 1]
    const float* W_hh  = (const float*)d_in[2];   // [80, 20]
    const float* W_out = (const float*)d_in[3];   // [1, 20]
    float* y = (float*)d_out;                      // [2048, 4096, 1]

    const int blocks = BB / 2;  // 2 batches per single-wave block -> 2048 = 2 waves/SIMD
    lstm_fused_kernel<<<dim3(blocks), dim3(64), 0, stream>>>(u, W_ih, W_hh, W_out, y);
}

// Round 2
// 819.022 us; speedup vs baseline: 1.1814x; 1.0305x over previous
//
#include <hip/hip_runtime.h>
#include <hip/hip_bf16.h>
#include <math.h>

// Problem constants: T=2048, B=4096, IN_S=1, H=20, OUT_S=1
#define TT 2048
#define BB 4096
#define HH 20

typedef float v2f __attribute__((ext_vector_type(2)));

#define L2E 1.4426950408889634f  // log2(e)

__device__ __forceinline__ float rcp_fast(float x)  { return __builtin_amdgcn_rcpf(x); }
__device__ __forceinline__ float exp2_fast(float x) { return __builtin_amdgcn_exp2f(x); }

// Backend selects v_pk_fma_f32 — no inline-asm pinning (R5 lesson).
__device__ __forceinline__ v2f pk_fma(v2f a, v2f b, v2f c) {
    return __builtin_elementwise_fma(a, b, c);
}

// One wave per block, TWO batches per wave (lanes [0..19],[20..39]); lanes
// 40/41 carry the W_out dot (y-offload, R9). R10 changes vs the 844us kernel:
//  (a) NO per-step asm memory barrier. R6-verified: the compiler's alias
//      analysis (hbuf write vs hs read, same array, no __restrict__) orders
//      the LDS ops and inserts the lgkmcnt wait itself. The full "memory"
//      clobber was pinning u-prefetch/y-store code outside the LDS-RT stall
//      window; without it the scheduler can sink independent work there.
//  (b) c off the h-critical-path: tanh(c) from |num| and sign(num) directly
//      (c = num*rcp(den), den>0, so |c| = |num|*r and sign(c)=sign(num)).
//      The kn=-2L2E*|num| mul overlaps the rcp; c=num*r retires off-path.
//  (c) 8-step inner unroll: u prefetched 8 ahead, y stored every 8 steps —
//      fewer vmcnt injections and loop overhead on the serial chain.
// Model (R10): wall = T x C(per-wave step); chains of all 2048 blocks run
// concurrently, so ONLY the per-step serial chain C matters. C ~= LDS
// write->read RT + dot issue + activation trans-chain.
__global__ __launch_bounds__(64, 2) void lstm_fused_kernel(
    const float* __restrict__ u,      // [T, B, 1]
    const float* __restrict__ W_ih,   // [4H, 1]
    const float* __restrict__ W_hh,   // [4H, H]
    const float* __restrict__ W_out,  // [1, H]
    float* __restrict__ y)            // [T, B, 1]
{
    // Single buffer. Compiler SEES the aliasing between write and reads ->
    // inserts the lgkmcnt wait itself (R6-verified correct; R7 showed
    // __restrict__ LDS pointers suppress it -> stale h).
    __shared__ __align__(16) float hbuf[4][HH];

    const int lane  = threadIdx.x;
    const int group = lane / HH;          // 0..3 (2,3 == y/idle)
    const int j     = lane - group * HH;  // 0..19
    const bool is_y = (lane >= 2 * HH) && (lane < 2 * HH + 2);  // lanes 40,41
    const int b_real = blockIdx.x * 2 + group;
    const bool active = (group < 2) && (b_real < BB);
    const int b = active ? b_real : 0;

    // h_{-1} = 0 (all groups incl. idle regions).
    for (int i = lane; i < 4 * HH; i += 64) ((float*)hbuf)[i] = 0.0f;
    asm volatile("" ::: "memory");  // one-time, outside the hot loop

    // ---- Weights in registers, packed along k: wg[g][m] = (w[2m], w[2m+1]).
    // Pre-scaled into exp2 domain: i,f,o rows * -log2(e); g row * -2*log2(e).
    v2f wg[4][HH / 2];
    const float gsc[4] = {-L2E, -L2E, -2.0f * L2E, -L2E};
    #pragma unroll
    for (int g = 0; g < 4; ++g) {
        #pragma unroll
        for (int m = 0; m < HH / 2; ++m) {
            wg[g][m].x = gsc[g] * W_hh[(g * HH + j) * HH + 2 * m];
            wg[g][m].y = gsc[g] * W_hh[(g * HH + j) * HH + 2 * m + 1];
        }
    }
    v2f wih2[4];
    #pragma unroll
    for (int g = 0; g < 4; ++g) { wih2[g].x = gsc[g] * W_ih[g * HH + j]; wih2[g].y = 0.0f; }

    // y-offload wiring: broadcast-source group per lane, W_out row for y-lanes.
    int bg = group;
    if (lane >= 2 * HH) {
        bg = is_y ? (lane - 2 * HH) : 2;  // lane40->group0's h, lane41->group1's
        if (is_y) {
            #pragma unroll
            for (int m = 0; m < HH / 2; ++m) {
                wg[0][m].x = W_out[2 * m];      // UNSCALED: a0 = dot(W_out, h)
                wg[0][m].y = W_out[2 * m + 1];
            }
            wih2[0].x = 0.0f;  // y has no u-term
        }
    }
    const v2f* hs = (const v2f*)(&hbuf[bg][0]);  // no restrict: must alias

    float c = 0.0f;
    const float* __restrict__ up = u + b;
    float* yp = y + blockIdx.x * 2 + (lane - 2 * HH);  // valid only on y-lanes

    float u_cur[8];
    #pragma unroll
    for (int k = 0; k < 8; ++k) u_cur[k] = up[(size_t)k * BB];

    for (int t8 = 0; t8 < TT; t8 += 8) {
        const int tn = (t8 + 8 < TT) ? (t8 + 8) : t8;
        float u_nxt[8];
        #pragma unroll
        for (int k = 0; k < 8; ++k) u_nxt[k] = up[(size_t)(tn + k) * BB];

        float y8[8];  // on y-lanes: y8[tt] = y_{t8+tt-1} (h broadcast read is one step late)

        #pragma unroll
        for (int tt = 0; tt < 8; ++tt) {
            // ---- read h_{t-1} as 10 pairs (compiler merges to ds_read_b128) ----
            v2f h2[10];
            #pragma unroll
            for (int m = 0; m < 10; ++m) h2[m] = hs[m];

            const float uv = u_cur[tt];
            const v2f uv2 = {uv, uv};
            v2f a0 = wih2[0] * uv2;   // v_pk_mul_f32; .y term is 0
            v2f a1 = wih2[1] * uv2;
            v2f a2 = wih2[2] * uv2;
            v2f a3 = wih2[3] * uv2;

            // 40 v_pk_fma_f32; 4 accumulators round-robin -> dep spacing
            // 4 insts (8 cyc) > 4-cyc FMA latency. o-gate (a3) last: its
            // result is needed ~40cy later than the others.
            #pragma unroll
            for (int m = 0; m < 10; ++m) {
                v2f hp = h2[m];
                a2 = pk_fma(wg[2][m], hp, a2);
                a1 = pk_fma(wg[1][m], hp, a1);
                a0 = pk_fma(wg[0][m], hp, a0);
                a3 = pk_fma(wg[3][m], hp, a3);
            }
            const float g2 = a2.x + a2.y;  // exp2-domain pre-acts
            const float g1 = a1.x + a1.y;
            const float g0 = a0.x + a0.y;  // (y-lanes: y value)
            const float g3 = a3.x + a3.y;
            y8[tt] = g0;                   // only consumed on y-lanes

            // ---- activations: 5 exp2, 2 rcp (merged denominators) ----
            const float eg = exp2_fast(g2);   // e^{-2 x_g}  (sign-safe: |x_g|<~6)
            const float ef = exp2_fast(g1);   // e^{-x_f}
            const float ei = exp2_fast(g0);   // e^{-x_i}
            const float eo = exp2_fast(g3);   // e^{-x_o}
            const float pg  = 1.0f + eg;
            const float pf  = 1.0f + ef;
            const float pi_ = 1.0f + ei;
            const float po  = 1.0f + eo;
            const float mg  = 1.0f - eg;      // sign of tanh(x_g) falls out naturally

            // c' = f*c + i*tanh(g), one rcp. c itself retires OFF the h-path:
            // tanh(c') needs only |num| (|c'| = |num|*r, r>0) and sign(num).
            const float m1  = pg * pi_;
            const float num = fmaf(c, m1, mg * pf);
            const float r   = rcp_fast(pf * m1);
            c = num * r;                               // for next step only
            const float kn  = (-2.0f * L2E) * fabsf(num);  // overlaps the rcp
            const float ec  = exp2_fast(kn * r);       // e^{-2|c|} <= 1, no overflow
            const float pc  = 1.0f + ec;
            const float mcs = copysignf(1.0f - ec, num);   // sign(c)==sign(num)
            const float h   = mcs * rcp_fast(po * pc);

            // ---- broadcast h_t. NO asm barrier: alias analysis orders the
            // LDS write vs next step's reads (R6-verified). ----
            hbuf[group][j] = h;
        }

        if (is_y) {
            #pragma unroll
            for (int k = 0; k < 8; ++k) {
                const int idx = t8 - 1 + k;
                if (idx >= 0) yp[(size_t)idx * BB] = y8[k];
            }
        }

        #pragma unroll
        for (int k = 0; k < 8; ++k) u_cur[k] = u_nxt[k];
    }

    // Epilogue: y_{T-1} from the final h broadcast (y-lanes only).
    {
        v2f ay = {0.0f, 0.0f};
        #pragma unroll
        for (int m = 0; m < 10; ++m) ay = pk_fma(wg[0][m], hs[m], ay);
        if (is_y) yp[(size_t)(TT - 1) * BB] = ay.x + ay.y;
    }
}

extern "C" void kernel_launch(void* const* d_in, const int* in_sizes, int n_in,
                              void* d_out, int out_size, void* d_ws, size_t ws_size,
                              hipStream_t stream) {
    const float* u     = (const float*)d_in[0];   // [2048, 4096, 1]
    const float* W_ih  = (const float*)d_in[1];   // [80, 1]
    const float* W_hh  = (const float*)d_in[2];   // [80, 20]
    const float* W_out = (const float*)d_in[3];   // [1, 20]
    float* y = (float*)d_out;                      // [2048, 4096, 1]

    const int blocks = BB / 2;  // 2 batches per single-wave block -> 2048 = 2 waves/SIMD
    lstm_fused_kernel<<<dim3(blocks), dim3(64), 0, stream>>>(u, W_ih, W_hh, W_out, y);
}

// Round 4
// 803.903 us; speedup vs baseline: 1.2036x; 1.0188x over previous
//
#include <hip/hip_runtime.h>
#include <hip/hip_bf16.h>
#include <math.h>

// Problem constants: T=2048, B=4096, IN_S=1, H=20, OUT_S=1
#define TT 2048
#define BB 4096
#define HH 20

typedef float v2f __attribute__((ext_vector_type(2)));

#define L2E 1.4426950408889634f  // log2(e)

__device__ __forceinline__ float rcp_fast(float x)  { return __builtin_amdgcn_rcpf(x); }
__device__ __forceinline__ float exp2_fast(float x) { return __builtin_amdgcn_exp2f(x); }

// Backend selects v_pk_fma_f32 — no inline-asm pinning of the FMA (R5 lesson).
__device__ __forceinline__ v2f pk_fma(v2f a, v2f b, v2f c) {
    return __builtin_elementwise_fma(a, b, c);
}

// One wave per block, TWO batches per wave (lanes [0..19],[20..39]); lanes
// 40/41 carry the W_out dot (y-offload, R9).
// R12 = R11 retry: PIN THE WEIGHTS IN VGPRS, but with SCALAR asm operands
// (the R11 container failure's only novel construct was a vector-typed
// "+v" asm operand; scalar float "+v" is the fully-standard path).
// Evidence for the pin: reported VGPR_Count=68, but resident state (wg=80
// floats + wih2 + u bufs + y8 + h2) needs >=140 regs. Only possible if the
// compiler REMATERIALIZES the weight loads inside the hot loop (W_hh is
// const __restrict__ with loop-invariant addresses -> reload is legal
// remat). That injects ~40 hidden L1 loads + vmcnt waits into every step's
// serial chain — invisible in FETCH_SIZE (L1 hits), visible as the
// ~500cy/step of unexplained stall. Identity-asm outputs are not remat-able
// -> forced resident. Budget: ~170 VGPR < 256 allowed by launch_bounds(64,2).
// Model (R10): wall = T x C(per-wave step); all 2048 chains run concurrently,
// so ONLY the per-step serial chain C matters.
__global__ __launch_bounds__(64, 2) void lstm_fused_kernel(
    const float* __restrict__ u,      // [T, B, 1]
    const float* __restrict__ W_ih,   // [4H, 1]
    const float* __restrict__ W_hh,   // [4H, H]
    const float* __restrict__ W_out,  // [1, H]
    float* __restrict__ y)            // [T, B, 1]
{
    // Single buffer. Compiler SEES the aliasing between write and reads ->
    // inserts the lgkmcnt wait itself (R6-verified correct; R7 showed
    // __restrict__ LDS pointers suppress it -> stale h).
    __shared__ __align__(16) float hbuf[4][HH];

    const int lane  = threadIdx.x;
    const int group = lane / HH;          // 0..3 (2,3 == y/idle)
    const int j     = lane - group * HH;  // 0..19
    const bool is_y = (lane >= 2 * HH) && (lane < 2 * HH + 2);  // lanes 40,41
    const int b_real = blockIdx.x * 2 + group;
    const bool active = (group < 2) && (b_real < BB);
    const int b = active ? b_real : 0;

    // h_{-1} = 0 (all groups incl. idle regions).
    for (int i = lane; i < 4 * HH; i += 64) ((float*)hbuf)[i] = 0.0f;
    asm volatile("" ::: "memory");  // one-time, outside the hot loop

    // ---- Weights in registers, packed along k: wg[g][m] = (w[2m], w[2m+1]).
    // Pre-scaled into exp2 domain: i,f,o rows * -log2(e); g row * -2*log2(e).
    v2f wg[4][HH / 2];
    const float gsc[4] = {-L2E, -L2E, -2.0f * L2E, -L2E};
    #pragma unroll
    for (int g = 0; g < 4; ++g) {
        #pragma unroll
        for (int m = 0; m < HH / 2; ++m) {
            wg[g][m].x = gsc[g] * W_hh[(g * HH + j) * HH + 2 * m];
            wg[g][m].y = gsc[g] * W_hh[(g * HH + j) * HH + 2 * m + 1];
        }
    }
    v2f wih2[4];
    #pragma unroll
    for (int g = 0; g < 4; ++g) { wih2[g].x = gsc[g] * W_ih[g * HH + j]; wih2[g].y = 0.0f; }

    // y-offload wiring: broadcast-source group per lane, W_out row for y-lanes.
    int bg = group;
    if (lane >= 2 * HH) {
        bg = is_y ? (lane - 2 * HH) : 2;  // lane40->group0's h, lane41->group1's
        if (is_y) {
            #pragma unroll
            for (int m = 0; m < HH / 2; ++m) {
                wg[0][m].x = W_out[2 * m];      // UNSCALED: a0 = dot(W_out, h)
                wg[0][m].y = W_out[2 * m + 1];
            }
            wih2[0].x = 0.0f;  // y has no u-term
        }
    }

    // ---- PIN: identity asm (scalar operands) makes each weight an asm
    // output -> the compiler cannot rematerialize the global load inside the
    // loop. (Placed after the y-lane overwrite so the pinned value is final.)
    #pragma unroll
    for (int g = 0; g < 4; ++g) {
        #pragma unroll
        for (int m = 0; m < HH / 2; ++m) {
            asm volatile("" : "+v"(wg[g][m].x), "+v"(wg[g][m].y));
        }
        asm volatile("" : "+v"(wih2[g].x));
    }

    const v2f* hs = (const v2f*)(&hbuf[bg][0]);  // no restrict: must alias

    float c = 0.0f;
    const float* __restrict__ up = u + b;
    float* yp = y + blockIdx.x * 2 + (lane - 2 * HH);  // valid only on y-lanes

    float u_cur[8];
    #pragma unroll
    for (int k = 0; k < 8; ++k) u_cur[k] = up[(size_t)k * BB];

    for (int t8 = 0; t8 < TT; t8 += 8) {
        const int tn = (t8 + 8 < TT) ? (t8 + 8) : t8;
        float u_nxt[8];
        #pragma unroll
        for (int k = 0; k < 8; ++k) u_nxt[k] = up[(size_t)(tn + k) * BB];

        float y8[8];  // on y-lanes: y8[tt] = y_{t8+tt-1} (h broadcast read is one step late)

        #pragma unroll
        for (int tt = 0; tt < 8; ++tt) {
            // ---- read h_{t-1} as 10 pairs (compiler merges to ds_read_b128) ----
            v2f h2[10];
            #pragma unroll
            for (int m = 0; m < 10; ++m) h2[m] = hs[m];

            const float uv = u_cur[tt];
            const v2f uv2 = {uv, uv};
            v2f a0 = wih2[0] * uv2;   // v_pk_mul_f32; .y term is 0
            v2f a1 = wih2[1] * uv2;
            v2f a2 = wih2[2] * uv2;
            v2f a3 = wih2[3] * uv2;

            // 40 v_pk_fma_f32; 4 accumulators round-robin -> dep spacing
            // 4 insts (8 cyc) > 4-cyc FMA latency. o-gate (a3) last: its
            // result is needed ~40cy later than the others.
            #pragma unroll
            for (int m = 0; m < 10; ++m) {
                v2f hp = h2[m];
                a2 = pk_fma(wg[2][m], hp, a2);
                a1 = pk_fma(wg[1][m], hp, a1);
                a0 = pk_fma(wg[0][m], hp, a0);
                a3 = pk_fma(wg[3][m], hp, a3);
            }
            const float g2 = a2.x + a2.y;  // exp2-domain pre-acts
            const float g1 = a1.x + a1.y;
            const float g0 = a0.x + a0.y;  // (y-lanes: y value)
            const float g3 = a3.x + a3.y;
            y8[tt] = g0;                   // only consumed on y-lanes

            // ---- activations: 5 exp2, 2 rcp (merged denominators) ----
            const float eg = exp2_fast(g2);   // e^{-2 x_g}  (sign-safe: |x_g|<~6)
            const float ef = exp2_fast(g1);   // e^{-x_f}
            const float ei = exp2_fast(g0);   // e^{-x_i}
            const float eo = exp2_fast(g3);   // e^{-x_o}
            const float pg  = 1.0f + eg;
            const float pf  = 1.0f + ef;
            const float pi_ = 1.0f + ei;
            const float po  = 1.0f + eo;
            const float mg  = 1.0f - eg;      // sign of tanh(x_g) falls out naturally

            // c' = f*c + i*tanh(g), one rcp. c itself retires OFF the h-path:
            // tanh(c') needs only |num| (|c'| = |num|*r, r>0) and sign(num).
            const float m1  = pg * pi_;
            const float num = fmaf(c, m1, mg * pf);
            const float r   = rcp_fast(pf * m1);
            c = num * r;                               // for next step only
            const float kn  = (-2.0f * L2E) * fabsf(num);  // overlaps the rcp
            const float ec  = exp2_fast(kn * r);       // e^{-2|c|} <= 1, no overflow
            const float pc  = 1.0f + ec;
            const float mcs = copysignf(1.0f - ec, num);   // sign(c)==sign(num)
            const float h   = mcs * rcp_fast(po * pc);

            // ---- broadcast h_t. NO asm barrier: alias analysis orders the
            // LDS write vs next step's reads (R6-verified). ----
            hbuf[group][j] = h;
        }

        if (is_y) {
            #pragma unroll
            for (int k = 0; k < 8; ++k) {
                const int idx = t8 - 1 + k;
                if (idx >= 0) yp[(size_t)idx * BB] = y8[k];
            }
        }

        #pragma unroll
        for (int k = 0; k < 8; ++k) u_cur[k] = u_nxt[k];
    }

    // Epilogue: y_{T-1} from the final h broadcast (y-lanes only).
    {
        v2f ay = {0.0f, 0.0f};
        #pragma unroll
        for (int m = 0; m < 10; ++m) ay = pk_fma(wg[0][m], hs[m], ay);
        if (is_y) yp[(size_t)(TT - 1) * BB] = ay.x + ay.y;
    }
}

extern "C" void kernel_launch(void* const* d_in, const int* in_sizes, int n_in,
                              void* d_out, int out_size, void* d_ws, size_t ws_size,
                              hipStream_t stream) {
    const float* u     = (const float*)d_in[0];   // [2048, 4096, 1]
    const float* W_ih  = (const float*)d_in[1];   // [80, 1]
    const float* W_hh  = (const float*)d_in[2];   // [80, 20]
    const float* W_out = (const float*)d_in[3];   // [1, 20]
    float* y = (float*)d_out;                      // [2048, 4096, 1]

    const int blocks = BB / 2;  // 2 batches per single-wave block -> 2048 = 2 waves/SIMD
    lstm_fused_kernel<<<dim3(blocks), dim3(64), 0, stream>>>(u, W_ih, W_hh, W_out, y);
}